// Round 6
// baseline (91.750 us; speedup 1.0000x reference)
//
#include <hip/hip_runtime.h>

// ---------------------------------------------------------------------------
// Conv2dfft == 3x3 SAME cross-correlation conv (pad=1) + bias.
// N=32, C=128, F=128, H=W=32.  Implicit-GEMM, bf16 MFMA 16x16x32.
// Round 6: BARRIER-FREE K-loop. All 4 c-chunks of x staged to LDS up front
// (65 KB of the 160 KB/CU), ONE __syncthreads, then 12 weight groups x 48
// MFMAs with af triple-buffered from L2 (prefetch distance 2) -- no barrier
// ever drains the in-flight weight loads (compiler's vmcnt(0)-before-barrier
// defeated the R3/R4 per-chunk-barrier versions). Two plain kernels
// (cooperative launch fails under graph capture -- R5).
// ---------------------------------------------------------------------------

typedef short bf16x8 __attribute__((ext_vector_type(8)));   // 8 bf16 (4 VGPR)
typedef short bf16x4 __attribute__((ext_vector_type(4)));   // 4 bf16 (2 VGPR)
typedef float f32x4  __attribute__((ext_vector_type(4)));   // MFMA 16x16 acc

__device__ __forceinline__ short f2bf(float f) {            // RNE fp32->bf16
  unsigned u = __builtin_bit_cast(unsigned, f);
  u = (u + 0x7fffu + ((u >> 16) & 1u)) >> 16;
  return (short)u;
}

// ---------------------------------------------------------------------------
// Prepass: weight (F,C,3,3) fp32 -> bf16 fragment-major:
//   bc2[chunk(4)*9+tap][fblk(8)][lane(64)][j(8)]
// A-frag elem j of lane (quad*16+l15) = W[f=fblk*16+l15][c=chunk*32+quad*8+j].
// Coalesced read (tid = linear w index), scattered 2-B writes (L2 absorbs).
// ---------------------------------------------------------------------------
__global__ __launch_bounds__(256) void conv_wprep(const float* __restrict__ w,
                                                  short* __restrict__ bc2) {
  int tid = blockIdx.x * 256 + threadIdx.x;    // [0, 147456)
  float v = w[tid];                            // coalesced
  int f   = tid / 1152;                        // w layout: f*1152 + c*9 + tap
  int rem = tid - f * 1152;
  int c   = rem / 9;
  int tap = rem - c * 9;
  int dst = ((((c >> 5) * 9 + tap) * 8 + (f >> 4)) * 512)   // [chunk*9+tap][fblk]
          + (((c >> 3) & 3) * 16 + (f & 15)) * 8            // lane = quad*16+l15
          + (c & 7);                                        // j
  bc2[dst] = f2bf(v);
}

// ---------------------------------------------------------------------------
// load_af: one weight group (chunk,p) = 3 q-taps x 4 f-tiles for this wave's
// f-half: 12 coalesced global_load_dwordx4 (uniform base + lane*16) from L2.
// ---------------------------------------------------------------------------
__device__ __forceinline__ void load_af(bf16x8* dst, const short* __restrict__ bc2,
                                        int grp, int fsel, int lane) {
  const short* base = bc2 + ((grp * 3 * 8 + fsel * 4) * 512) + lane * 8;
#pragma unroll
  for (int q = 0; q < 3; ++q)
#pragma unroll
    for (int mt = 0; mt < 4; ++mt)
      dst[q * 4 + mt] = *(const bf16x8*)(base + (q * 8 + mt) * 512);
}

// ---------------------------------------------------------------------------
// Main: 256 blocks (1/CU) x 256 threads (4 waves, 1/SIMD).
// Block = image n_img, output rows h0..h0+3, 32 cols, 128 f.
// Wave: fsel=wv&1 (f-half), s_rowb=(wv>>1)*2; 4x4 acc of 16x16 tiles.
// ---------------------------------------------------------------------------
__global__ __launch_bounds__(256, 1) void conv_main(
    const float* __restrict__ x, const short* __restrict__ bc2,
    const float* __restrict__ bias, float* __restrict__ out) {
  // xs[chunk(4)][row(6)][col(34)][c(32 + 8 pad)] ; stride 40 shorts = 80 B:
  // bf16x8 reads 16-B aligned (ds_read_b128), 8 accesses/bank (conflict-free).
  __shared__ __align__(16) short xs[4][6 * 34 * 40];      // 65280 B

  const int t    = threadIdx.x;
  const int lane = t & 63;
  const int wv   = t >> 6;
  const int n_img = blockIdx.x >> 3;
  const int h0    = (blockIdx.x & 7) << 2;

  const int l15  = lane & 15;
  const int quad = lane >> 4;
  const int fsel   = wv & 1;
  const int f_off  = fsel * 64;
  const int s_rowb = (wv >> 1) * 2;

  const int w_ = t & 31;          // staged output col (coalesced)
  const int g  = t >> 5;          // c-quad group [0,8)
  const float* xb = x + n_img * 128 * 1024;

  // af triple-buffer; groups 0,1 issued immediately (L2/HBM, overlap staging)
  bf16x8 af0[12], af1[12], af2[12];
  load_af(af0, bc2, 0, fsel, lane);
  load_af(af1, bc2, 1, fsel, lane);

  // Zero halo cols (col 0 == w=-1, col 33 == w=32) in all 4 chunk buffers.
#pragma unroll
  for (int i = 0; i < 2; ++i) {
    int idx = i * 256 + t;
    if (idx < 384) {                           // 4ch x 6r x 2col x 8(int2)
      int ch = idx / 96, rem = idx % 96;
      int r = rem / 16, rem2 = rem % 16;
      int col = (rem2 / 8) * 33, q4 = rem2 % 8;
      *(int2*)&xs[ch][(r * 34 + col) * 40 + q4 * 4] = make_int2(0, 0);
    }
  }

  // ---- stage ALL x: 4 chunks, no intervening barriers (pipelined burst) ----
#pragma unroll
  for (int chunk = 0; chunk < 4; ++chunk) {
    float xv[24];
#pragma unroll
    for (int r = 0; r < 6; ++r) {
      int hr = h0 - 1 + r;
      bool ok = (unsigned)hr < 32u;
#pragma unroll
      for (int cc = 0; cc < 4; ++cc)
        xv[r * 4 + cc] =
            ok ? xb[((chunk * 32 + g * 4 + cc) * 32 + hr) * 32 + w_] : 0.f;
    }
#pragma unroll
    for (int r = 0; r < 6; ++r) {
      bf16x4 v = { f2bf(xv[r*4+0]), f2bf(xv[r*4+1]), f2bf(xv[r*4+2]), f2bf(xv[r*4+3]) };
      *(bf16x4*)&xs[chunk][(r * 34 + w_ + 1) * 40 + g * 4] = v;
    }
  }
  __syncthreads();                 // the ONLY barrier in the kernel

  f32x4 acc[4][4] = {};

  // ---- barrier-free K-loop: 12 groups (chunk,p), af prefetch distance 2 ----
#pragma unroll
  for (int grp = 0; grp < 12; ++grp) {
    const int chunk = grp / 3, p = grp % 3;
    const bf16x8* cur = (grp % 3 == 0) ? af0 : (grp % 3 == 1) ? af1 : af2;
    if (grp + 2 <= 11) {           // stays in flight: no barriers ahead
      bf16x8* nxt = ((grp + 2) % 3 == 0) ? af0
                  : ((grp + 2) % 3 == 1) ? af1 : af2;
      load_af(nxt, bc2, grp + 2, fsel, lane);
    }
    const short* xbuf = xs[chunk];
#pragma unroll
    for (int q = 0; q < 3; ++q) {
      bf16x8 bfr[4];
#pragma unroll
      for (int nt = 0; nt < 4; ++nt) {
        int r   = s_rowb + (nt >> 1) + p;
        int col = (nt & 1) * 16 + l15 + q;
        bfr[nt] = *(const bf16x8*)&xbuf[(r * 34 + col) * 40 + quad * 8];
      }
#pragma unroll
      for (int mt = 0; mt < 4; ++mt)
#pragma unroll
        for (int nt = 0; nt < 4; ++nt)
          acc[mt][nt] = __builtin_amdgcn_mfma_f32_16x16x32_bf16(
              cur[q * 4 + mt], bfr[nt], acc[mt][nt], 0, 0, 0);
    }
  }

  // ---- epilogue: C/D layout col=lane&15 (w), row=quad*4+reg (f) ----
#pragma unroll
  for (int nt = 0; nt < 4; ++nt) {
    int h = h0 + s_rowb + (nt >> 1);
    int w_out = (nt & 1) * 16 + l15;
#pragma unroll
    for (int mt = 0; mt < 4; ++mt) {
#pragma unroll
      for (int reg = 0; reg < 4; ++reg) {
        int f = f_off + mt * 16 + quad * 4 + reg;
        out[((n_img * 128 + f) * 32 + h) * 32 + w_out] = acc[mt][nt][reg] + bias[f];
      }
    }
  }
}

// ---------------------------------------------------------------------------
extern "C" void kernel_launch(void* const* d_in, const int* in_sizes, int n_in,
                              void* d_out, int out_size, void* d_ws, size_t ws_size,
                              hipStream_t stream) {
  const float* x    = (const float*)d_in[0];   // 32*128*32*32
  const float* w    = (const float*)d_in[1];   // 128*128*3*3
  const float* bias = (const float*)d_in[2];   // 128
  float* out = (float*)d_out;                  // 32*128*32*32
  short* bc2 = (short*)d_ws;                   // 294,912 B fragment-major weights

  conv_wprep<<<576, 256, 0, stream>>>(w, bc2);
  conv_main<<<256, 256, 0, stream>>>(x, bc2, bias, out);
}

// Round 7
// 89.081 us; speedup vs baseline: 1.0300x; 1.0300x over previous
//
#include <hip/hip_runtime.h>

// ---------------------------------------------------------------------------
// Conv2dfft == 3x3 SAME cross-correlation conv (pad=1) + bias.
// N=32, C=128, F=128, H=W=32.  Implicit-GEMM, bf16 MFMA 16x16x32.
// Round 7: R3 structure (best: 87.5us) + COALESCED EPILOGUE. acc is
// transposed per-wave through LDS (pad 36 -> aligned b128, <=2-way banks)
// and stored as global_store_dwordx4 covering full 128-B (f,h)-rows,
// replacing 64 scattered 64-B-segment scalar stores per thread.
// K-loop/staging/wprep identical to R3 (R6 proved overlap > barrier-free).
// ---------------------------------------------------------------------------

typedef short bf16x8 __attribute__((ext_vector_type(8)));   // 8 bf16 (4 VGPR)
typedef short bf16x4 __attribute__((ext_vector_type(4)));   // 4 bf16 (2 VGPR)
typedef float f32x4  __attribute__((ext_vector_type(4)));   // MFMA 16x16 acc

__device__ __forceinline__ short f2bf(float f) {            // RNE fp32->bf16
  unsigned u = __builtin_bit_cast(unsigned, f);
  u = (u + 0x7fffu + ((u >> 16) & 1u)) >> 16;
  return (short)u;
}

// ---------------------------------------------------------------------------
// Prepass: weight (F,C,3,3) fp32 -> bf16 fragment-major:
//   bc2[chunk(4)*9+tap][fblk(8)][lane(64)][j(8)]
// A-frag elem j of lane (quad*16+l15) = W[f=fblk*16+l15][c=chunk*32+quad*8+j].
// ---------------------------------------------------------------------------
__global__ __launch_bounds__(256) void conv_wprep(const float* __restrict__ w,
                                                  short* __restrict__ bc2) {
  int tid = blockIdx.x * 256 + threadIdx.x;    // [0, 147456)
  float v = w[tid];                            // coalesced
  int f   = tid / 1152;                        // w layout: f*1152 + c*9 + tap
  int rem = tid - f * 1152;
  int c   = rem / 9;
  int tap = rem - c * 9;
  int dst = ((((c >> 5) * 9 + tap) * 8 + (f >> 4)) * 512)
          + (((c >> 3) & 3) * 16 + (f & 15)) * 8
          + (c & 7);
  bc2[dst] = f2bf(v);
}

// load one weight group (chunk,p): 12 coalesced global_load_dwordx4 from L2.
__device__ __forceinline__ void load_af(bf16x8* dst, const short* __restrict__ bc2,
                                        int chunk, int p, int fsel, int lane) {
  const short* base = bc2 + (((chunk * 9 + p * 3) * 8 + fsel * 4) * 512) + lane * 8;
#pragma unroll
  for (int q = 0; q < 3; ++q)
#pragma unroll
    for (int mt = 0; mt < 4; ++mt)
      dst[q * 4 + mt] = *(const bf16x8*)(base + (q * 8 + mt) * 512);
}

// ---------------------------------------------------------------------------
// Main: 256 blocks (1/CU) x 256 threads (4 waves).
// Block = image n_img, output rows h0..h0+3, 32 cols, 128 f.
// Wave: fsel=wv&1 (f-half), s_rowb=(wv>>1)*2; 4x4 acc of 16x16 tiles.
// ---------------------------------------------------------------------------
__global__ __launch_bounds__(256, 1) void conv_main(
    const float* __restrict__ x, const short* __restrict__ bc2,
    const float* __restrict__ bias, float* __restrict__ out) {
  // smem serves two phases:
  //  K-loop:  xs = (short*)smem : [2][6*34*40] bf16 (32,640 B), stride 40
  //           shorts = 80 B -> 16-B-aligned ds_read_b128, conflict-free.
  //  epilogue: tr = smem + wv*2304 : per-wave [64][36] floats (pad 36 ->
  //           144-B rows: b128-aligned, <=2-way banks). Aliased; guarded by
  //           one __syncthreads after the K-loop.
  __shared__ __align__(16) float smem[9216];              // 36,864 B
  short* xs = (short*)smem;

  const int t    = threadIdx.x;
  const int lane = t & 63;
  const int wv   = t >> 6;
  const int n_img = blockIdx.x >> 3;
  const int h0    = (blockIdx.x & 7) << 2;

  const int l15  = lane & 15;
  const int quad = lane >> 4;
  const int fsel   = wv & 1;
  const int f_off  = fsel * 64;
  const int s_rowb = (wv >> 1) * 2;

  const int w_ = t & 31;          // staged output col (coalesced)
  const int g  = t >> 5;          // c-quad group [0,8)
  const float* xb = x + n_img * 128 * 1024;

  // bias preload (in flight during staging; used only in epilogue)
  float bv[16];
#pragma unroll
  for (int mt = 0; mt < 4; ++mt)
#pragma unroll
    for (int reg = 0; reg < 4; ++reg)
      bv[mt * 4 + reg] = bias[f_off + mt * 16 + quad * 4 + reg];

  // af double-buffer: group = chunk*3+p, 12 frags (48 VGPRs) each.
  bf16x8 afA[12], afB[12];
  load_af(afA, bc2, 0, 0, fsel, lane);   // group 0 in flight ASAP

  // Zero halo cols (col 0 == w=-1, col 33 == w=32) in BOTH buffers, once.
  if (t < 192) {
    int buf = t / 96, rem = t % 96;
    int r = rem / 16, rem2 = rem % 16;
    int colsel = rem2 / 8, q4 = rem2 % 8;
    *(int2*)&xs[buf * 8160 + (r * 34 + colsel * 33) * 40 + q4 * 4] = make_int2(0, 0);
  }

  f32x4 acc[4][4] = {};
  float xv[24];

  // ---- chunk 0 x -> regs -> buf 0 ----
#pragma unroll
  for (int r = 0; r < 6; ++r) {
    int hr = h0 - 1 + r;
    bool ok = (unsigned)hr < 32u;
#pragma unroll
    for (int cc = 0; cc < 4; ++cc)
      xv[r * 4 + cc] = ok ? xb[((g * 4 + cc) * 32 + hr) * 32 + w_] : 0.f;
  }
#pragma unroll
  for (int r = 0; r < 6; ++r) {
    bf16x4 v = { f2bf(xv[r*4+0]), f2bf(xv[r*4+1]), f2bf(xv[r*4+2]), f2bf(xv[r*4+3]) };
    *(bf16x4*)&xs[(r * 34 + w_ + 1) * 40 + g * 4] = v;
  }
  __syncthreads();

#pragma unroll
  for (int chunk = 0; chunk < 4; ++chunk) {
    // ---- prefetch next chunk's x into regs (hides under 144 MFMAs) ----
    if (chunk < 3) {
#pragma unroll
      for (int r = 0; r < 6; ++r) {
        int hr = h0 - 1 + r;
        bool ok = (unsigned)hr < 32u;
#pragma unroll
        for (int cc = 0; cc < 4; ++cc)
          xv[r * 4 + cc] =
              ok ? xb[(((chunk + 1) * 32 + g * 4 + cc) * 32 + hr) * 32 + w_] : 0.f;
      }
    }
    const short* xbuf = xs + (chunk & 1) * 8160;
#pragma unroll
    for (int p = 0; p < 3; ++p) {
      const int grp = chunk * 3 + p;
      const bf16x8* cur = (grp & 1) ? afB : afA;
      bf16x8*       nxt = (grp & 1) ? afA : afB;
      if (grp < 11)
        load_af(nxt, bc2, (grp + 1) / 3, (grp + 1) % 3, fsel, lane);
#pragma unroll
      for (int q = 0; q < 3; ++q) {
        bf16x8 bfr[4];
#pragma unroll
        for (int nt = 0; nt < 4; ++nt) {
          int r   = s_rowb + (nt >> 1) + p;
          int col = (nt & 1) * 16 + l15 + q;
          bfr[nt] = *(const bf16x8*)&xbuf[(r * 34 + col) * 40 + quad * 8];
        }
#pragma unroll
        for (int mt = 0; mt < 4; ++mt)
#pragma unroll
          for (int nt = 0; nt < 4; ++nt)
            acc[mt][nt] = __builtin_amdgcn_mfma_f32_16x16x32_bf16(
                cur[q * 4 + mt], bfr[nt], acc[mt][nt], 0, 0, 0);
      }
    }
    // ---- stage prefetched x into the other buffer ----
    if (chunk < 3) {
#pragma unroll
      for (int r = 0; r < 6; ++r) {
        bf16x4 v = { f2bf(xv[r*4+0]), f2bf(xv[r*4+1]), f2bf(xv[r*4+2]), f2bf(xv[r*4+3]) };
        *(bf16x4*)&xs[((chunk + 1) & 1) * 8160 + (r * 34 + w_ + 1) * 40 + g * 4] = v;
      }
      __syncthreads();
    }
  }

  // ---- epilogue: per-wave LDS transpose -> full-line dwordx4 stores ----
  __syncthreads();                 // xs reads done before tr aliases xs
  float* tr = smem + wv * 2304;    // [64][36] floats, wave-private
#pragma unroll
  for (int hsel = 0; hsel < 2; ++hsel) {
    // scatter this h-row's 32 acc values into tr[f_local][col]
#pragma unroll
    for (int mt = 0; mt < 4; ++mt)
#pragma unroll
      for (int cs = 0; cs < 2; ++cs) {
        int nt  = hsel * 2 + cs;
        int col = cs * 16 + l15;
        int fl  = mt * 16 + quad * 4;
#pragma unroll
        for (int reg = 0; reg < 4; ++reg)
          tr[(fl + reg) * 36 + col] = acc[mt][nt][reg] + bv[mt * 4 + reg];
      }
    // read back coalesced: 8 lanes cover one full 128-B (f,h)-row
    const int h = h0 + s_rowb + hsel;
#pragma unroll
    for (int i = 0; i < 8; ++i) {
      int u  = i * 64 + lane;      // [0,512)
      int fl = u >> 3;             // [0,64)
      int wq = (u & 7) * 4;        // [0,32) step 4
      f32x4 v = *(const f32x4*)&tr[fl * 36 + wq];
      *(f32x4*)&out[((n_img * 128 + f_off + fl) * 32 + h) * 32 + wq] = v;
    }
  }
}

// ---------------------------------------------------------------------------
extern "C" void kernel_launch(void* const* d_in, const int* in_sizes, int n_in,
                              void* d_out, int out_size, void* d_ws, size_t ws_size,
                              hipStream_t stream) {
  const float* x    = (const float*)d_in[0];   // 32*128*32*32
  const float* w    = (const float*)d_in[1];   // 128*128*3*3
  const float* bias = (const float*)d_in[2];   // 128
  float* out = (float*)d_out;                  // 32*128*32*32
  short* bc2 = (short*)d_ws;                   // 294,912 B fragment-major weights

  conv_wprep<<<576, 256, 0, stream>>>(w, bc2);
  conv_main<<<256, 256, 0, stream>>>(x, bc2, bias, out);
}

// Round 8
// 87.339 us; speedup vs baseline: 1.0505x; 1.0199x over previous
//
#include <hip/hip_runtime.h>

// ---------------------------------------------------------------------------
// Conv2dfft == 3x3 SAME cross-correlation conv (pad=1) + bias.
// N=32, C=128, F=128, H=W=32.  Implicit-GEMM, bf16 MFMA 16x16x32.
// Round 8: INTER-BLOCK overlap. 512 blocks x 256 thr, 2 blocks/CU
// (__launch_bounds__(256,2)): independent blocks do NOT share barriers, so
// one block's compute covers the other's prologue/barrier-drain/epilogue.
// Strip = 2 output rows (halved); wave = 64f x 1 row (4x2 acc, 32 VGPR).
// K-loop structure = R3 (best so far): x double-buffered per 32-c chunk,
// af weight fragments double-buffered global->VGPR, scalar-store epilogue.
// ---------------------------------------------------------------------------

typedef short bf16x8 __attribute__((ext_vector_type(8)));   // 8 bf16 (4 VGPR)
typedef short bf16x4 __attribute__((ext_vector_type(4)));   // 4 bf16 (2 VGPR)
typedef float f32x4  __attribute__((ext_vector_type(4)));   // MFMA 16x16 acc

__device__ __forceinline__ short f2bf(float f) {            // RNE fp32->bf16
  unsigned u = __builtin_bit_cast(unsigned, f);
  u = (u + 0x7fffu + ((u >> 16) & 1u)) >> 16;
  return (short)u;
}

// ---------------------------------------------------------------------------
// Prepass: weight (F,C,3,3) fp32 -> bf16 fragment-major:
//   bc2[chunk(4)*9+tap][fblk(8)][lane(64)][j(8)]
// A-frag elem j of lane (quad*16+l15) = W[f=fblk*16+l15][c=chunk*32+quad*8+j].
// ---------------------------------------------------------------------------
__global__ __launch_bounds__(256) void conv_wprep(const float* __restrict__ w,
                                                  short* __restrict__ bc2) {
  int tid = blockIdx.x * 256 + threadIdx.x;    // [0, 147456)
  float v = w[tid];                            // coalesced
  int f   = tid / 1152;                        // w layout: f*1152 + c*9 + tap
  int rem = tid - f * 1152;
  int c   = rem / 9;
  int tap = rem - c * 9;
  int dst = ((((c >> 5) * 9 + tap) * 8 + (f >> 4)) * 512)
          + (((c >> 3) & 3) * 16 + (f & 15)) * 8
          + (c & 7);
  bc2[dst] = f2bf(v);
}

// load one weight group (chunk,p): 12 coalesced global_load_dwordx4 from L2.
__device__ __forceinline__ void load_af(bf16x8* dst, const short* __restrict__ bc2,
                                        int chunk, int p, int fsel, int lane) {
  const short* base = bc2 + (((chunk * 9 + p * 3) * 8 + fsel * 4) * 512) + lane * 8;
#pragma unroll
  for (int q = 0; q < 3; ++q)
#pragma unroll
    for (int mt = 0; mt < 4; ++mt)
      dst[q * 4 + mt] = *(const bf16x8*)(base + (q * 8 + mt) * 512);
}

// ---------------------------------------------------------------------------
// Main: 512 blocks (2/CU) x 256 threads (4 waves).
// Block = image n_img, output rows h0..h0+1 (strip of 2), 32 cols, 128 f.
// Wave: fsel=wv&1 (f-half), s_row=wv>>1 (one row); 4x2 acc of 16x16 tiles.
// ---------------------------------------------------------------------------
__global__ __launch_bounds__(256, 2) void conv_main(
    const float* __restrict__ x, const short* __restrict__ bc2,
    const float* __restrict__ bias, float* __restrict__ out) {
  // xs[buf][row(4)][col(34)][c(32 + 8 pad)] ; stride 40 shorts = 80 B:
  // bf16x8 reads 16-B aligned (ds_read_b128), 8 accesses/bank (conflict-free).
  __shared__ __align__(16) short xs[2][4 * 34 * 40];      // 21,760 B

  const int t    = threadIdx.x;
  const int lane = t & 63;
  const int wv   = t >> 6;
  const int n_img = blockIdx.x >> 4;
  const int h0    = (blockIdx.x & 15) << 1;

  const int l15  = lane & 15;
  const int quad = lane >> 4;
  const int fsel  = wv & 1;
  const int f_off = fsel * 64;
  const int s_row = wv >> 1;      // this wave's output row within the strip

  const int w_ = t & 31;          // staged output col (coalesced)
  const int g  = t >> 5;          // staging group [0,8)
  const float* xb = x + n_img * 128 * 1024;

  // af double-buffer: group = chunk*3+p, 12 frags (48 VGPRs) each.
  bf16x8 afA[12], afB[12];
  load_af(afA, bc2, 0, 0, fsel, lane);   // group 0 in flight ASAP

  // Zero halo cols (col 0 == w=-1, col 33 == w=32) in BOTH buffers, once.
  if (t < 128) {
    int buf = t >> 6, rem = t & 63;      // 2 buf x 4 r x 2 col x 8 int2
    int r = rem >> 4, rem2 = rem & 15;
    int colsel = rem2 >> 3, q4 = rem2 & 7;
    *(int2*)&xs[buf][(r * 34 + colsel * 33) * 40 + q4 * 4] = make_int2(0, 0);
  }

  f32x4 acc[4][2] = {};           // [mt(f)][nt(col-half)]
  float xv[16];

  // ---- chunk 0 x -> regs -> buf 0 : rows h0-1..h0+2, 32 c ----
#pragma unroll
  for (int i = 0; i < 4; ++i) {
    int idx = i * 8 + g;          // [0,32) = r*8 + cq
    int r = idx >> 3, cq = idx & 7;
    int hr = h0 - 1 + r;
    bool ok = (unsigned)hr < 32u;
#pragma unroll
    for (int cc = 0; cc < 4; ++cc)
      xv[i * 4 + cc] = ok ? xb[(cq * 4 + cc) * 1024 + hr * 32 + w_] : 0.f;
  }
#pragma unroll
  for (int i = 0; i < 4; ++i) {
    int idx = i * 8 + g;
    int r = idx >> 3, cq = idx & 7;
    bf16x4 v = { f2bf(xv[i*4+0]), f2bf(xv[i*4+1]), f2bf(xv[i*4+2]), f2bf(xv[i*4+3]) };
    *(bf16x4*)&xs[0][(r * 34 + w_ + 1) * 40 + cq * 4] = v;
  }
  __syncthreads();

#pragma unroll
  for (int chunk = 0; chunk < 4; ++chunk) {
    // ---- prefetch next chunk's x into regs (hides under 72 MFMAs) ----
    if (chunk < 3) {
#pragma unroll
      for (int i = 0; i < 4; ++i) {
        int idx = i * 8 + g;
        int r = idx >> 3, cq = idx & 7;
        int hr = h0 - 1 + r;
        bool ok = (unsigned)hr < 32u;
#pragma unroll
        for (int cc = 0; cc < 4; ++cc)
          xv[i * 4 + cc] =
              ok ? xb[((chunk + 1) * 32 + cq * 4 + cc) * 1024 + hr * 32 + w_] : 0.f;
      }
    }
    const short* xbuf = xs[chunk & 1];
#pragma unroll
    for (int p = 0; p < 3; ++p) {
      const int grp = chunk * 3 + p;
      const bf16x8* cur = (grp & 1) ? afB : afA;
      bf16x8*       nxt = (grp & 1) ? afA : afB;
      if (grp < 11)
        load_af(nxt, bc2, (grp + 1) / 3, (grp + 1) % 3, fsel, lane);
#pragma unroll
      for (int q = 0; q < 3; ++q) {
        bf16x8 bfr[2];
#pragma unroll
        for (int nt = 0; nt < 2; ++nt) {
          int r   = s_row + p;
          int col = nt * 16 + l15 + q;
          bfr[nt] = *(const bf16x8*)&xbuf[(r * 34 + col) * 40 + quad * 8];
        }
#pragma unroll
        for (int mt = 0; mt < 4; ++mt)
#pragma unroll
          for (int nt = 0; nt < 2; ++nt)
            acc[mt][nt] = __builtin_amdgcn_mfma_f32_16x16x32_bf16(
                cur[q * 4 + mt], bfr[nt], acc[mt][nt], 0, 0, 0);
      }
    }
    // ---- stage prefetched x into the other buffer ----
    if (chunk < 3) {
#pragma unroll
      for (int i = 0; i < 4; ++i) {
        int idx = i * 8 + g;
        int r = idx >> 3, cq = idx & 7;
        bf16x4 v = { f2bf(xv[i*4+0]), f2bf(xv[i*4+1]), f2bf(xv[i*4+2]), f2bf(xv[i*4+3]) };
        *(bf16x4*)&xs[(chunk + 1) & 1][(r * 34 + w_ + 1) * 40 + cq * 4] = v;
      }
      __syncthreads();
    }
  }

  // ---- epilogue: C/D layout col=lane&15 (w), row=quad*4+reg (f) ----
  const int h = h0 + s_row;
#pragma unroll
  for (int nt = 0; nt < 2; ++nt) {
    int w_out = nt * 16 + l15;
#pragma unroll
    for (int mt = 0; mt < 4; ++mt) {
#pragma unroll
      for (int reg = 0; reg < 4; ++reg) {
        int f = f_off + mt * 16 + quad * 4 + reg;
        out[((n_img * 128 + f) * 32 + h) * 32 + w_out] = acc[mt][nt][reg] + bias[f];
      }
    }
  }
}

// ---------------------------------------------------------------------------
extern "C" void kernel_launch(void* const* d_in, const int* in_sizes, int n_in,
                              void* d_out, int out_size, void* d_ws, size_t ws_size,
                              hipStream_t stream) {
  const float* x    = (const float*)d_in[0];   // 32*128*32*32
  const float* w    = (const float*)d_in[1];   // 128*128*3*3
  const float* bias = (const float*)d_in[2];   // 128
  float* out = (float*)d_out;                  // 32*128*32*32
  short* bc2 = (short*)d_ws;                   // 294,912 B fragment-major weights

  conv_wprep<<<576, 256, 0, stream>>>(w, bc2);
  conv_main<<<512, 256, 0, stream>>>(x, bc2, bias, out);
}